// Round 3
// baseline (2441.527 us; speedup 1.0000x reference)
//
#include <hip/hip_runtime.h>
#include <math.h>

// Problem constants
#define Bc    64
#define Cc    512
#define Fc    48
#define NTOT  32768          // B*C sequences
#define TT    49             // tokens per sequence (48 features + cls)
// attn scale 0.5 * log2(e): softmax done in exp2 domain (v_exp_f32 is 2^x)
#define QSCALE 0.72134752044448169f
// gelu(g) ~= g / (1 + exp2(C1*g + C2*g^3))  (validated in R2, absmax unchanged)
#define GC1 (-2.3022082f)
#define GC2 (-0.10294324f)

typedef __attribute__((ext_vector_type(8))) short bf16x8;
typedef __attribute__((ext_vector_type(4))) short short4v;
typedef __attribute__((ext_vector_type(4))) float f32x4;

#define EXP2(x) __builtin_amdgcn_exp2f(x)
#define RCP(x)  __builtin_amdgcn_rcpf(x)
#define MFMA(a,b,c) __builtin_amdgcn_mfma_f32_16x16x32_bf16((a),(b),(c),0,0,0)

// fp32 -> bf16 with round-to-nearest-even (bit trick; no NaNs in this net)
__device__ __forceinline__ short f2b(float f) {
    unsigned u = __builtin_bit_cast(unsigned, f);
    u = (u + 0x7fffu + ((u >> 16) & 1u)) >> 16;
    return (short)u;
}

// ============================================================================
// Kernel 1: one wave (64 lanes) per sequence. lane = token row (49 real + 15 pad).
// MFMA fragment layout (guide-verified for 16x16x32 bf16):
//   A: row = lane&15, k = (lane>>4)*8 + i   (i = 0..7)
//   B: col = lane&15, k = (lane>>4)*8 + i
//   D: col = lane&15, row = (lane>>4)*4 + r (r = 0..3)
// K=16 GEMMs: lanes >= 32 (k >= 16) carry zero frags.
// scores: k = head dim (0..3): only lanes < 16, frag elems 0..3 are real.
// ============================================================================
__global__ __launch_bounds__(64)
void enc_kernel(const float* __restrict__ cf,  const float* __restrict__ fe,
                const float* __restrict__ fb,  const float* __restrict__ cls_tok,
                const float* __restrict__ te,  const int*   __restrict__ role_ids,
                const float* __restrict__ ln1_s, const float* __restrict__ ln1_b,
                const float* __restrict__ qkv_w, const float* __restrict__ qkv_b,
                const float* __restrict__ out_w, const float* __restrict__ out_b,
                const float* __restrict__ ln2_s, const float* __restrict__ ln2_b,
                const float* __restrict__ ff1_w, const float* __restrict__ ff1_b,
                const float* __restrict__ ff2_w, const float* __restrict__ ff2_b,
                const float* __restrict__ c2h_w, const float* __restrict__ c2h_b,
                float* __restrict__ out, float* __restrict__ ws_cls, int use_ws)
{
    const int n  = blockIdx.x;
    const int b  = n >> 9;
    const int c  = n & 511;
    const int ln = threadIdx.x;
    const int q4 = ln & 15;
    const int g4 = ln >> 4;

    // Bank-audited LDS (strides chosen for conflict-free b64/b128 + alignment):
    __shared__ __align__(16) short Hs[64][20];   // LN output bf16 (rows 49..63 zeroed)
    __shared__ __align__(16) short Qs[4][64][4]; // [head][tok][dh], QSCALE folded
    __shared__ __align__(16) short Ks[4][64][4];
    __shared__ __align__(16) short VsT[16][72];  // [dim][tok] (transposed for PV B-frags)
    __shared__ __align__(16) short Pb[16][68];   // per-Mtile P rows / FF1 gelu buffer
    __shared__ __align__(16) short CTs[64][16];  // ctx bf16 [tok][dim]
    __shared__ __align__(16) float Sb[64][20];   // fp32 GEMM result for residual adds

    const bf16x8 z8 = (bf16x8){0,0,0,0,0,0,0,0};
    const f32x4  z4 = (f32x4){0.f,0.f,0.f,0.f};

    // ---- embedding: x (residual stream) in registers, row = lane ----
    float x[16];
    if (ln == 0) {
        #pragma unroll
        for (int d = 0; d < 16; ++d) x[d] = cls_tok[d];
    } else if (ln < TT) {
        const int f = ln - 1;
        const float s = cf[((long)b * Fc + f) * Cc + c];
        const int role = role_ids[f];
        #pragma unroll
        for (int d = 0; d < 16; ++d)
            x[d] = fmaf(s, fe[f*16+d], fb[f*16+d] + te[role*16+d]);
    } else {
        #pragma unroll
        for (int d = 0; d < 16; ++d) x[d] = 0.f;
    }

    for (int l = 0; l < 2; ++l) {
        // ================= LN1 -> Hs (bf16, pad rows forced 0) =================
        {
            float mu = 0.f;
            #pragma unroll
            for (int d = 0; d < 16; ++d) mu += x[d];
            mu *= 0.0625f;
            float var = 0.f;
            #pragma unroll
            for (int d = 0; d < 16; ++d) { float dv = x[d]-mu; var = fmaf(dv,dv,var); }
            var *= 0.0625f;
            const float rr = rsqrtf(var + 1e-5f);
            const bool act = (ln < TT);
            #pragma unroll
            for (int d = 0; d < 16; ++d) {
                float h = (x[d]-mu)*rr*ln1_s[l*16+d] + ln1_b[l*16+d];
                Hs[ln][d] = act ? f2b(h) : (short)0;
            }
        }

        // ================= QKV: Hs(64x16) @ Wqkv(16x48) =================
        {
            // A-frags (shared across the 3 N-tiles)
            bf16x8 af[4];
            #pragma unroll
            for (int mt = 0; mt < 4; ++mt) {
                bf16x8 a = z8;
                if (ln < 32) {
                    const short* p0 = &Hs[mt*16+q4][g4*8];
                    short4v v0 = *(const short4v*)p0;
                    short4v v1 = *(const short4v*)(p0+4);
                    a[0]=v0[0];a[1]=v0[1];a[2]=v0[2];a[3]=v0[3];
                    a[4]=v1[0];a[5]=v1[1];a[6]=v1[2];a[7]=v1[3];
                }
                af[mt] = a;
            }
            const float* Wl = qkv_w + l*16*48;
            #pragma unroll
            for (int nt = 0; nt < 3; ++nt) {
                bf16x8 bw = z8;
                if (ln < 32) {
                    const float* wp = Wl + (g4*8)*48 + nt*16 + q4;
                    #pragma unroll
                    for (int i = 0; i < 8; ++i) bw[i] = f2b(wp[i*48]);
                }
                const float bqk = qkv_b[l*48 + nt*16 + q4];
                #pragma unroll
                for (int mt = 0; mt < 4; ++mt) {
                    f32x4 cf_ = MFMA(af[mt], bw, z4);
                    #pragma unroll
                    for (int r = 0; r < 4; ++r) {
                        const int tok = mt*16 + g4*4 + r;
                        const float v = cf_[r] + bqk;
                        if (nt == 0)      Qs[q4>>2][tok][q4&3] = f2b(v * QSCALE);
                        else if (nt == 1) Ks[q4>>2][tok][q4&3] = f2b(v);
                        else              VsT[q4][tok]         = f2b(v);
                    }
                }
            }
        }

        // ================= attention (per head): scores -> softmax -> PV =================
        #pragma unroll 1
        for (int h = 0; h < 4; ++h) {
            bf16x8 aq[4], bk[4];
            #pragma unroll
            for (int i4 = 0; i4 < 4; ++i4) {
                bf16x8 t = z8;
                if (ln < 16) {
                    short4v v = *(const short4v*)&Qs[h][i4*16+ln][0];
                    t[0]=v[0];t[1]=v[1];t[2]=v[2];t[3]=v[3];
                }
                aq[i4] = t;
                bf16x8 t2 = z8;
                if (ln < 16) {
                    short4v v = *(const short4v*)&Ks[h][i4*16+ln][0];
                    t2[0]=v[0];t2[1]=v[1];t2[2]=v[2];t2[3]=v[3];
                }
                bk[i4] = t2;
            }
            #pragma unroll 1
            for (int mt = 0; mt < 4; ++mt) {
                f32x4 sc[4];
                #pragma unroll
                for (int nt = 0; nt < 4; ++nt) sc[nt] = MFMA(aq[mt], bk[nt], z4);
                // softmax over cols (ktok): cols real iff nt*16+q4 <= 48
                float pv[4][4];
                float rs[4] = {0.f,0.f,0.f,0.f};
                #pragma unroll
                for (int nt = 0; nt < 4; ++nt)
                    #pragma unroll
                    for (int r = 0; r < 4; ++r) {
                        float e = EXP2(sc[nt][r]);
                        if (nt == 3 && q4 != 0) e = 0.f;   // mask pad k-cols 49..63
                        pv[nt][r] = e;
                        rs[r] += e;
                    }
                #pragma unroll
                for (int r = 0; r < 4; ++r) {
                    rs[r] += __shfl_xor(rs[r], 1);
                    rs[r] += __shfl_xor(rs[r], 2);
                    rs[r] += __shfl_xor(rs[r], 4);
                    rs[r] += __shfl_xor(rs[r], 8);
                }
                #pragma unroll
                for (int nt = 0; nt < 4; ++nt)
                    #pragma unroll
                    for (int r = 0; r < 4; ++r)
                        Pb[g4*4+r][nt*16+q4] = f2b(pv[nt][r] * RCP(rs[r]));
                // PV: P(16x64) @ V(64x16-with-4-real-cols), K=64 as 2 K-steps
                f32x4 cv = z4;
                #pragma unroll
                for (int ks = 0; ks < 2; ++ks) {
                    bf16x8 ap;
                    const short* p0 = &Pb[q4][ks*32 + g4*8];
                    short4v v0 = *(const short4v*)p0;
                    short4v v1 = *(const short4v*)(p0+4);
                    ap[0]=v0[0];ap[1]=v0[1];ap[2]=v0[2];ap[3]=v0[3];
                    ap[4]=v1[0];ap[5]=v1[1];ap[6]=v1[2];ap[7]=v1[3];
                    bf16x8 bv = z8;
                    if (q4 < 4) bv = *(const bf16x8*)&VsT[h*4+q4][ks*32 + g4*8];
                    cv = MFMA(ap, bv, cv);
                }
                if (q4 < 4) {
                    #pragma unroll
                    for (int r = 0; r < 4; ++r)
                        CTs[mt*16 + g4*4 + r][h*4 + q4] = f2b(cv[r]);
                }
            }
        }

        // ================= out-proj: CT(64x16) @ Wout(16x16) + residual =================
        {
            bf16x8 bw = z8;
            if (ln < 32) {
                const float* wp = out_w + l*256 + (g4*8)*16 + q4;
                #pragma unroll
                for (int i = 0; i < 8; ++i) bw[i] = f2b(wp[i*16]);
            }
            const float bo = out_b[l*16 + q4];
            #pragma unroll
            for (int mt = 0; mt < 4; ++mt) {
                bf16x8 a = z8;
                if (ln < 32) a = *(const bf16x8*)&CTs[mt*16+q4][g4*8];
                f32x4 cf_ = MFMA(a, bw, z4);
                #pragma unroll
                for (int r = 0; r < 4; ++r)
                    Sb[mt*16 + g4*4 + r][q4] = cf_[r] + bo;
            }
            #pragma unroll
            for (int j = 0; j < 4; ++j) {
                f32x4 v = *(const f32x4*)&Sb[ln][j*4];
                #pragma unroll
                for (int k = 0; k < 4; ++k) x[j*4+k] += v[k];
            }
        }

        // ================= LN2 -> Hs =================
        {
            float mu = 0.f;
            #pragma unroll
            for (int d = 0; d < 16; ++d) mu += x[d];
            mu *= 0.0625f;
            float var = 0.f;
            #pragma unroll
            for (int d = 0; d < 16; ++d) { float dv = x[d]-mu; var = fmaf(dv,dv,var); }
            var *= 0.0625f;
            const float rr = rsqrtf(var + 1e-5f);
            const bool act = (ln < TT);
            #pragma unroll
            for (int d = 0; d < 16; ++d) {
                float h = (x[d]-mu)*rr*ln2_s[l*16+d] + ln2_b[l*16+d];
                Hs[ln][d] = act ? f2b(h) : (short)0;
            }
        }

        // ================= FF: H2 @ W1(16x64) -> gelu -> @ W2(64x16) + residual =====
        {
            bf16x8 af[4];
            #pragma unroll
            for (int mt = 0; mt < 4; ++mt) {
                bf16x8 a = z8;
                if (ln < 32) {
                    const short* p0 = &Hs[mt*16+q4][g4*8];
                    short4v v0 = *(const short4v*)p0;
                    short4v v1 = *(const short4v*)(p0+4);
                    a[0]=v0[0];a[1]=v0[1];a[2]=v0[2];a[3]=v0[3];
                    a[4]=v1[0];a[5]=v1[1];a[6]=v1[2];a[7]=v1[3];
                }
                af[mt] = a;
            }
            bf16x8 b1w[4];
            #pragma unroll
            for (int nt = 0; nt < 4; ++nt) {
                bf16x8 t = z8;
                if (ln < 32) {
                    const float* wp = ff1_w + l*1024 + (g4*8)*64 + nt*16 + q4;
                    #pragma unroll
                    for (int i = 0; i < 8; ++i) t[i] = f2b(wp[i*64]);
                }
                b1w[nt] = t;
            }
            bf16x8 b2w[2];
            #pragma unroll
            for (int ks = 0; ks < 2; ++ks) {
                bf16x8 t;
                const float* wp = ff2_w + l*1024 + (ks*32 + g4*8)*16 + q4;
                #pragma unroll
                for (int i = 0; i < 8; ++i) t[i] = f2b(wp[i*16]);
                b2w[ks] = t;
            }
            float bb1[4];
            #pragma unroll
            for (int nt = 0; nt < 4; ++nt) bb1[nt] = ff1_b[l*64 + nt*16 + q4];
            const float bb2 = ff2_b[l*16 + q4];

            #pragma unroll 1
            for (int mt = 0; mt < 4; ++mt) {
                #pragma unroll
                for (int nt = 0; nt < 4; ++nt) {
                    f32x4 gg = MFMA(af[mt], b1w[nt], z4);
                    #pragma unroll
                    for (int r = 0; r < 4; ++r) {
                        float g = gg[r] + bb1[nt];
                        float u = g * fmaf(GC2, g*g, GC1);
                        float ge = g * RCP(1.0f + EXP2(u));
                        Pb[g4*4+r][nt*16+q4] = f2b(ge);   // Pb reused as gelu buffer
                    }
                }
                f32x4 cv = z4;
                #pragma unroll
                for (int ks = 0; ks < 2; ++ks) {
                    bf16x8 ap;
                    const short* p0 = &Pb[q4][ks*32 + g4*8];
                    short4v v0 = *(const short4v*)p0;
                    short4v v1 = *(const short4v*)(p0+4);
                    ap[0]=v0[0];ap[1]=v0[1];ap[2]=v0[2];ap[3]=v0[3];
                    ap[4]=v1[0];ap[5]=v1[1];ap[6]=v1[2];ap[7]=v1[3];
                    cv = MFMA(ap, b2w[ks], cv);
                }
                #pragma unroll
                for (int r = 0; r < 4; ++r)
                    Sb[mt*16 + g4*4 + r][q4] = cv[r] + bb2;
            }
            #pragma unroll
            for (int j = 0; j < 4; ++j) {
                f32x4 v = *(const f32x4*)&Sb[ln][j*4];
                #pragma unroll
                for (int k = 0; k < 4; ++k) x[j*4+k] += v[k];
            }
        }
    }

    // ================= head =================
    if (use_ws) {
        // write cls row (lane 0's x) to ws, lane d holds x_cls[d]
        float cv = 0.f;
        #pragma unroll
        for (int d = 0; d < 16; ++d) {
            float t = __shfl(x[d], 0);
            if (ln == d) cv = t;
        }
        if (ln < 16) ws_cls[(long)n*16 + ln] = cv;
    } else {
        // fallback: direct (scattered) head
        float clsr[16];
        #pragma unroll
        for (int d = 0; d < 16; ++d) clsr[d] = __shfl(x[d], 0);
        #pragma unroll
        for (int oo = 0; oo < 4; ++oo) {
            const int o = ln*4 + oo;
            float a = c2h_b[o];
            #pragma unroll
            for (int d = 0; d < 16; ++d) a = fmaf(clsr[d], c2h_w[d*256+o], a);
            out[((long)b*256 + o)*Cc + c] = a;
        }
    }
}

// ============================================================================
// Kernel 2: head GEMM + transposed store, fully coalesced.
// grid = (b, o-chunk of 16): 64*16 blocks, 256 threads, c in 2 passes.
// out[b][O][c] = cls[b*512+c] . c2h_w[:, O] + bias[O]
// ============================================================================
__global__ __launch_bounds__(256)
void head_kernel(const float* __restrict__ ws_cls, const float* __restrict__ W,
                 const float* __restrict__ bias, float* __restrict__ out)
{
    const int bb = blockIdx.x >> 4;
    const int o0 = (blockIdx.x & 15) << 4;
    const int tid = threadIdx.x;
    #pragma unroll
    for (int cp = 0; cp < 2; ++cp) {
        const int cc = cp*256 + tid;
        const long nn = (long)bb*512 + cc;
        float xr[16];
        #pragma unroll
        for (int j = 0; j < 4; ++j)
            ((f32x4*)xr)[j] = ((const f32x4*)(ws_cls + nn*16))[j];
        #pragma unroll
        for (int oo = 0; oo < 16; ++oo) {
            const int O = o0 + oo;
            float a = bias[O];
            #pragma unroll
            for (int d = 0; d < 16; ++d) a = fmaf(xr[d], W[d*256+O], a);
            out[((long)bb*256 + O)*512 + cc] = a;
        }
    }
}

extern "C" void kernel_launch(void* const* d_in, const int* in_sizes, int n_in,
                              void* d_out, int out_size, void* d_ws, size_t ws_size,
                              hipStream_t stream) {
    const float* cf       = (const float*)d_in[0];
    const float* fe       = (const float*)d_in[1];
    const float* fb       = (const float*)d_in[2];
    const float* cls_tok  = (const float*)d_in[3];
    const float* te       = (const float*)d_in[4];
    const int*   role_ids = (const int*)  d_in[5];
    const float* ln1_s    = (const float*)d_in[6];
    const float* ln1_b    = (const float*)d_in[7];
    const float* qkv_w    = (const float*)d_in[8];
    const float* qkv_b    = (const float*)d_in[9];
    const float* out_w    = (const float*)d_in[10];
    const float* out_b    = (const float*)d_in[11];
    const float* ln2_s    = (const float*)d_in[12];
    const float* ln2_b    = (const float*)d_in[13];
    const float* ff1_w    = (const float*)d_in[14];
    const float* ff1_b    = (const float*)d_in[15];
    const float* ff2_w    = (const float*)d_in[16];
    const float* ff2_b    = (const float*)d_in[17];
    const float* c2h_w    = (const float*)d_in[18];
    const float* c2h_b    = (const float*)d_in[19];
    float* out = (float*)d_out;

    const int use_ws = (ws_size >= (size_t)NTOT * 16 * 4) ? 1 : 0;

    enc_kernel<<<NTOT, 64, 0, stream>>>(cf, fe, fb, cls_tok, te, role_ids,
                                        ln1_s, ln1_b, qkv_w, qkv_b, out_w, out_b,
                                        ln2_s, ln2_b, ff1_w, ff1_b, ff2_w, ff2_b,
                                        c2h_w, c2h_b, out, (float*)d_ws, use_ws);
    if (use_ws)
        head_kernel<<<Bc*16, 256, 0, stream>>>((const float*)d_ws, c2h_w, c2h_b, out);
}

// Round 4
// 511.734 us; speedup vs baseline: 4.7711x; 4.7711x over previous
//
#include <hip/hip_runtime.h>
#include <math.h>

// Problem constants
#define Bc    64
#define Cc    512
#define Fc    48
#define NTOT  32768
#define TT    49
#define NS    5            // sequences per 256-thread block
// attn scale 0.5 * log2(e) folded into q-columns of qkv_w at pack time
#define QSCALE 0.72134752044448169f
// gelu(g) ~= g / (1 + exp2(C1*g + C2*g^3))  (validated R2/R3)
#define GC1 (-2.3022082f)
#define GC2 (-0.10294324f)

#define EXP2(x) __builtin_amdgcn_exp2f(x)
#define RCP(x)  __builtin_amdgcn_rcpf(x)

using h2 = decltype(__builtin_amdgcn_cvt_pkrtz(0.f, 0.f));   // v2f16

__device__ __forceinline__ h2 PK(float a, float b) {         // round-toward-zero pack
    return __builtin_amdgcn_cvt_pkrtz(a, b);
}
__device__ __forceinline__ unsigned H2U(h2 h) { return __builtin_bit_cast(unsigned, h); }
__device__ __forceinline__ h2 U2H(unsigned u) { return __builtin_bit_cast(h2, u); }

__device__ __forceinline__ float DOT2(h2 a, h2 b, float c) {
#if __has_builtin(__builtin_amdgcn_fdot2)
    return __builtin_amdgcn_fdot2(a, b, c, false);   // fp32 accumulate
#else
    return fmaf((float)a[0], (float)b[0], fmaf((float)a[1], (float)b[1], c));
#endif
}
__device__ __forceinline__ unsigned pack_rte(float a, float b) {  // accurate pack (setup)
    h2 h; h[0] = (_Float16)a; h[1] = (_Float16)b;
    return __builtin_bit_cast(unsigned, h);
}

// ---- ws dword offsets ----
#define OFF_QKVW 0        // [l][j<48][dp<8] h2 pairs over d; q cols pre-scaled   (768)
#define OFF_QKVB 768      // [l][48] f32, q pre-scaled                            (96)
#define OFF_OUTW 864      // [l][d<16][dp<8] pairs over dd                        (256)
#define OFF_OUTB 1120     // [l][16] f32                                          (32)
#define OFF_FF1W 1152     // [l][j<64][dp<8] pairs over d                         (1024)
#define OFF_FF1B 2176     // [l][64] f32                                          (128)
#define OFF_FF2W 2304     // [l][jp<32][d<16] pairs over j                        (1024)
#define OFF_FF2B 3328     // [l][16] f32                                          (32)
#define OFF_C2HW 3360     // [o<256][dp<8] pairs over d                           (2048)
#define OFF_C2HB 5408     // [256] f32                                            (256)
#define OFF_FBTE 5664     // [f<48][d<16] f32 = fb + te[role]                     (768)
#define WS_DWORDS 6432

__global__ __launch_bounds__(256)
void pack_kernel(const float* __restrict__ qkv_w, const float* __restrict__ qkv_b,
                 const float* __restrict__ out_w, const float* __restrict__ out_b,
                 const float* __restrict__ ff1_w, const float* __restrict__ ff1_b,
                 const float* __restrict__ ff2_w, const float* __restrict__ ff2_b,
                 const float* __restrict__ c2h_w, const float* __restrict__ c2h_b,
                 const float* __restrict__ fb,    const float* __restrict__ te,
                 const int*   __restrict__ role,  unsigned* __restrict__ ws)
{
    const int t = threadIdx.x;
    float* wsf = (float*)ws;
    for (int i = t; i < 768; i += 256) {          // qkvW pairs over d
        int dp = i & 7, jl = i >> 3, j = jl % 48, l = jl / 48;
        float w0 = qkv_w[(l*16 + 2*dp    )*48 + j];
        float w1 = qkv_w[(l*16 + 2*dp + 1)*48 + j];
        if (j < 16) { w0 *= QSCALE; w1 *= QSCALE; }
        ws[OFF_QKVW + i] = pack_rte(w0, w1);
    }
    for (int i = t; i < 96; i += 256) {           // qkvB
        int j = i % 48;
        wsf[OFF_QKVB + i] = qkv_b[i] * (j < 16 ? QSCALE : 1.0f);
    }
    for (int i = t; i < 256; i += 256) {          // outW pairs over dd
        int dp = i & 7, dl = i >> 3, d = dl % 16, l = dl / 16;
        ws[OFF_OUTW + i] = pack_rte(out_w[l*256 + (2*dp)*16 + d],
                                    out_w[l*256 + (2*dp+1)*16 + d]);
    }
    for (int i = t; i < 32; i += 256) wsf[OFF_OUTB + i] = out_b[i];
    for (int i = t; i < 1024; i += 256) {         // ff1W pairs over d
        int dp = i & 7, jl = i >> 3, j = jl % 64, l = jl / 64;
        ws[OFF_FF1W + i] = pack_rte(ff1_w[l*1024 + (2*dp)*64 + j],
                                    ff1_w[l*1024 + (2*dp+1)*64 + j]);
    }
    for (int i = t; i < 128; i += 256) wsf[OFF_FF1B + i] = ff1_b[i];
    for (int i = t; i < 1024; i += 256) {         // ff2W pairs over j
        int d = i & 15, jpl = i >> 4, jp = jpl % 32, l = jpl / 32;
        ws[OFF_FF2W + i] = pack_rte(ff2_w[l*1024 + (2*jp)*16 + d],
                                    ff2_w[l*1024 + (2*jp+1)*16 + d]);
    }
    for (int i = t; i < 32; i += 256) wsf[OFF_FF2B + i] = ff2_b[i];
    for (int i = t; i < 2048; i += 256) {         // c2hW pairs over d
        int dp = i & 7, o = i >> 3;
        ws[OFF_C2HW + i] = pack_rte(c2h_w[(2*dp)*256 + o], c2h_w[(2*dp+1)*256 + o]);
    }
    for (int i = t; i < 256; i += 256) wsf[OFF_C2HB + i] = c2h_b[i];
    for (int i = t; i < 768; i += 256) {          // fbte = fb + te[role]
        int d = i & 15, f = i >> 4;
        wsf[OFF_FBTE + i] = fb[f*16 + d] + te[role[f]*16 + d];
    }
}

// Per-seq LDS: K rows as f16 dim-pairs (stride 3 uint4 = 48B, b128-aligned);
// V as f16 KEY-pair dwords: Vp[pair][d] = (v[2p][d], v[2p+1][d]) -> PV is dot2
// over keys with fp32 accumulation. Pad key 49: Kp row zero -> p = 1 -> lsum -= 1,
// V high half zero.
struct __align__(16) SeqSh {
    uint4 Kp[50][3];
    uint4 Vp[25][5];
    unsigned clsP[8];
};

__global__ __launch_bounds__(256, 2)
void enc_kernel(const float* __restrict__ cf,  const float* __restrict__ fe,
                const float* __restrict__ cls_tok,
                const float* __restrict__ ln1_s, const float* __restrict__ ln1_b,
                const float* __restrict__ ln2_s, const float* __restrict__ ln2_b,
                const unsigned* __restrict__ wsp, float* __restrict__ out)
{
    const unsigned ut = threadIdx.x;
    const int seq = ut / 49u;
    const int row = ut - seq * 49u;
    const int n0  = blockIdx.x * NS;
    const int n   = n0 + seq;
    const bool act = (seq < NS) && (n < NTOT);
    const int b = n >> 9, c = n & 511;

    __shared__ SeqSh S[NS];
    const float* wsf = (const float*)wsp;

    // ---- embedding ----
    float x[16];
    if (act) {
        if (row == 0) {
            #pragma unroll
            for (int d = 0; d < 16; ++d) x[d] = cls_tok[d];
        } else {
            const int f = row - 1;
            const float s = cf[((long)b * Fc + f) * Cc + c];
            const float4* fep = (const float4*)(fe + f*16);
            const float4* fbp = (const float4*)(wsf + OFF_FBTE + f*16);
            #pragma unroll
            for (int j = 0; j < 4; ++j) {
                float4 e = fep[j], t4 = fbp[j];
                x[4*j+0] = fmaf(s, e.x, t4.x); x[4*j+1] = fmaf(s, e.y, t4.y);
                x[4*j+2] = fmaf(s, e.z, t4.z); x[4*j+3] = fmaf(s, e.w, t4.w);
            }
        }
    } else {
        #pragma unroll
        for (int d = 0; d < 16; ++d) x[d] = 0.f;
    }

    const h2 ONE = PK(1.f, 1.f);

    for (int l = 0; l < 2; ++l) {
        h2 hp[8], qp[8];
        // ---- LN1 + pack ----
        if (act) {
            float mu = 0.f;
            #pragma unroll
            for (int d = 0; d < 16; ++d) mu += x[d];
            mu *= 0.0625f;
            float var = 0.f;
            #pragma unroll
            for (int d = 0; d < 16; ++d) { float dv = x[d]-mu; var = fmaf(dv,dv,var); }
            const float rr = rsqrtf(var*0.0625f + 1e-5f);
            float hf[16];
            #pragma unroll
            for (int d = 0; d < 16; ++d)
                hf[d] = (x[d]-mu)*rr*ln1_s[l*16+d] + ln1_b[l*16+d];
            #pragma unroll
            for (int p = 0; p < 8; ++p) hp[p] = PK(hf[2*p], hf[2*p+1]);

            // ---- QKV via dot2 (weights uniform -> scalar loads) ----
            const unsigned* W = wsp + OFF_QKVW + l*384;
            const float* Bb = wsf + OFF_QKVB + l*48;
            #pragma unroll
            for (int j = 0; j < 16; j += 2) {      // q (pre-scaled)
                float a0 = Bb[j], a1 = Bb[j+1];
                #pragma unroll
                for (int dp = 0; dp < 8; ++dp) {
                    a0 = DOT2(hp[dp], U2H(W[ j   *8+dp]), a0);
                    a1 = DOT2(hp[dp], U2H(W[(j+1)*8+dp]), a1);
                }
                qp[j>>1] = PK(a0, a1);
            }
            unsigned kdw[8];
            #pragma unroll
            for (int j = 0; j < 16; j += 2) {      // k
                float a0 = Bb[16+j], a1 = Bb[17+j];
                #pragma unroll
                for (int dp = 0; dp < 8; ++dp) {
                    a0 = DOT2(hp[dp], U2H(W[(16+j)*8+dp]), a0);
                    a1 = DOT2(hp[dp], U2H(W[(17+j)*8+dp]), a1);
                }
                kdw[j>>1] = H2U(PK(a0, a1));
            }
            float vf[16];
            #pragma unroll
            for (int j = 0; j < 16; ++j) {         // v
                float a = Bb[32+j];
                #pragma unroll
                for (int dp = 0; dp < 8; ++dp)
                    a = DOT2(hp[dp], U2H(W[(32+j)*8+dp]), a);
                vf[j] = a;
            }
            S[seq].Kp[row][0] = make_uint4(kdw[0],kdw[1],kdw[2],kdw[3]);
            S[seq].Kp[row][1] = make_uint4(kdw[4],kdw[5],kdw[6],kdw[7]);
            if (row < 48) {
                _Float16* vh = (_Float16*)&S[seq].Vp[row>>1][0];
                const int pr = row & 1;
                #pragma unroll
                for (int d = 0; d < 16; ++d) vh[2*d + pr] = (_Float16)vf[d];
            } else {   // row 48 owns pair 24 fully; key 49 half = 0
                unsigned* vw = (unsigned*)&S[seq].Vp[24][0];
                #pragma unroll
                for (int d = 0; d < 16; ++d) vw[d] = H2U(PK(vf[d], 0.f));
            }
            if (row == 0) {
                const uint4 z = make_uint4(0,0,0,0);
                S[seq].Kp[49][0] = z; S[seq].Kp[49][1] = z;
            }
        }
        __syncthreads();   // K/V tile ready

        if (act) {
            // ---- attention: key-pair loop, no-max softmax in exp2 domain ----
            float ctx[16];
            #pragma unroll
            for (int d = 0; d < 16; ++d) ctx[d] = 0.f;
            float ls0=0.f, ls1=0.f, ls2=0.f, ls3=0.f;
            #pragma unroll 5
            for (int kp = 0; kp < 25; ++kp) {
                const uint4 ka0 = S[seq].Kp[2*kp  ][0], ka1 = S[seq].Kp[2*kp  ][1];
                const uint4 kb0 = S[seq].Kp[2*kp+1][0], kb1 = S[seq].Kp[2*kp+1][1];
                float sa0 = DOT2(qp[0],U2H(ka0.x), DOT2(qp[1],U2H(ka0.y), 0.f));
                float sb0 = DOT2(qp[0],U2H(kb0.x), DOT2(qp[1],U2H(kb0.y), 0.f));
                float sa1 = DOT2(qp[2],U2H(ka0.z), DOT2(qp[3],U2H(ka0.w), 0.f));
                float sb1 = DOT2(qp[2],U2H(kb0.z), DOT2(qp[3],U2H(kb0.w), 0.f));
                float sa2 = DOT2(qp[4],U2H(ka1.x), DOT2(qp[5],U2H(ka1.y), 0.f));
                float sb2 = DOT2(qp[4],U2H(kb1.x), DOT2(qp[5],U2H(kb1.y), 0.f));
                float sa3 = DOT2(qp[6],U2H(ka1.z), DOT2(qp[7],U2H(ka1.w), 0.f));
                float sb3 = DOT2(qp[6],U2H(kb1.z), DOT2(qp[7],U2H(kb1.w), 0.f));
                const h2 pp0 = PK(EXP2(sa0), EXP2(sb0));
                const h2 pp1 = PK(EXP2(sa1), EXP2(sb1));
                const h2 pp2 = PK(EXP2(sa2), EXP2(sb2));
                const h2 pp3 = PK(EXP2(sa3), EXP2(sb3));
                ls0 = DOT2(pp0, ONE, ls0); ls1 = DOT2(pp1, ONE, ls1);
                ls2 = DOT2(pp2, ONE, ls2); ls3 = DOT2(pp3, ONE, ls3);
                const uint4 v0 = S[seq].Vp[kp][0], v1 = S[seq].Vp[kp][1];
                const uint4 v2 = S[seq].Vp[kp][2], v3 = S[seq].Vp[kp][3];
                ctx[ 0]=DOT2(pp0,U2H(v0.x),ctx[ 0]); ctx[ 1]=DOT2(pp0,U2H(v0.y),ctx[ 1]);
                ctx[ 2]=DOT2(pp0,U2H(v0.z),ctx[ 2]); ctx[ 3]=DOT2(pp0,U2H(v0.w),ctx[ 3]);
                ctx[ 4]=DOT2(pp1,U2H(v1.x),ctx[ 4]); ctx[ 5]=DOT2(pp1,U2H(v1.y),ctx[ 5]);
                ctx[ 6]=DOT2(pp1,U2H(v1.z),ctx[ 6]); ctx[ 7]=DOT2(pp1,U2H(v1.w),ctx[ 7]);
                ctx[ 8]=DOT2(pp2,U2H(v2.x),ctx[ 8]); ctx[ 9]=DOT2(pp2,U2H(v2.y),ctx[ 9]);
                ctx[10]=DOT2(pp2,U2H(v2.z),ctx[10]); ctx[11]=DOT2(pp2,U2H(v2.w),ctx[11]);
                ctx[12]=DOT2(pp3,U2H(v3.x),ctx[12]); ctx[13]=DOT2(pp3,U2H(v3.y),ctx[13]);
                ctx[14]=DOT2(pp3,U2H(v3.z),ctx[14]); ctx[15]=DOT2(pp3,U2H(v3.w),ctx[15]);
            }
            // pad key 49 contributed exp2(0)=1 per head
            ls0 -= 1.f; ls1 -= 1.f; ls2 -= 1.f; ls3 -= 1.f;
            const float i0 = RCP(ls0), i1 = RCP(ls1), i2 = RCP(ls2), i3 = RCP(ls3);
            #pragma unroll
            for (int d = 0; d < 4;  ++d) ctx[d] *= i0;
            #pragma unroll
            for (int d = 4; d < 8;  ++d) ctx[d] *= i1;
            #pragma unroll
            for (int d = 8; d < 12; ++d) ctx[d] *= i2;
            #pragma unroll
            for (int d = 12; d < 16; ++d) ctx[d] *= i3;

            // ---- out-proj + residual ----
            h2 cp[8];
            #pragma unroll
            for (int p = 0; p < 8; ++p) cp[p] = PK(ctx[2*p], ctx[2*p+1]);
            const unsigned* OW = wsp + OFF_OUTW + l*128;
            const float* OB = wsf + OFF_OUTB + l*16;
            #pragma unroll
            for (int d = 0; d < 16; ++d) {
                float a = OB[d];
                #pragma unroll
                for (int dp = 0; dp < 8; ++dp) a = DOT2(cp[dp], U2H(OW[d*8+dp]), a);
                x[d] += a;
            }

            // ---- LN2 + pack ----
            float mu = 0.f;
            #pragma unroll
            for (int d = 0; d < 16; ++d) mu += x[d];
            mu *= 0.0625f;
            float var = 0.f;
            #pragma unroll
            for (int d = 0; d < 16; ++d) { float dv = x[d]-mu; var = fmaf(dv,dv,var); }
            const float rr = rsqrtf(var*0.0625f + 1e-5f);
            float hf[16];
            #pragma unroll
            for (int d = 0; d < 16; ++d)
                hf[d] = (x[d]-mu)*rr*ln2_s[l*16+d] + ln2_b[l*16+d];
            #pragma unroll
            for (int p = 0; p < 8; ++p) hp[p] = PK(hf[2*p], hf[2*p+1]);

            // ---- FF: 16->64->gelu->16, j-pair fused, all dot2 ----
            const unsigned* F1 = wsp + OFF_FF1W + l*512;
            const float*    B1 = wsf + OFF_FF1B + l*64;
            const unsigned* F2 = wsp + OFF_FF2W + l*512;
            float acc2[16];
            #pragma unroll
            for (int d = 0; d < 16; ++d) acc2[d] = wsf[OFF_FF2B + l*16 + d];
            #pragma unroll 4
            for (int jp = 0; jp < 32; ++jp) {
                float g0 = B1[2*jp], g1 = B1[2*jp+1];
                #pragma unroll
                for (int dp = 0; dp < 8; ++dp) {
                    g0 = DOT2(hp[dp], U2H(F1[(2*jp  )*8+dp]), g0);
                    g1 = DOT2(hp[dp], U2H(F1[(2*jp+1)*8+dp]), g1);
                }
                const float u0 = g0 * fmaf(GC2, g0*g0, GC1);
                const float e0 = g0 * RCP(1.0f + EXP2(u0));
                const float u1 = g1 * fmaf(GC2, g1*g1, GC1);
                const float e1 = g1 * RCP(1.0f + EXP2(u1));
                const h2 gp = PK(e0, e1);
                #pragma unroll
                for (int d = 0; d < 16; ++d)
                    acc2[d] = DOT2(gp, U2H(F2[jp*16+d]), acc2[d]);
            }
            #pragma unroll
            for (int d = 0; d < 16; ++d) x[d] += acc2[d];
        }
        __syncthreads();   // attn readers done before next layer overwrites LDS
    }

    // ---- head: cls row packed to LDS, lane ut owns output col o = ut ----
    if (act && row == 0) {
        #pragma unroll
        for (int p = 0; p < 8; ++p) S[seq].clsP[p] = H2U(PK(x[2*p], x[2*p+1]));
    }
    __syncthreads();

    const uint4* cw = (const uint4*)(wsp + OFF_C2HW + ut*8);
    const uint4 w0 = cw[0], w1 = cw[1];
    const float bt = wsf[OFF_C2HB + ut];
    #pragma unroll
    for (int oo = 0; oo < NS; ++oo) {
        const int n2 = n0 + oo;
        if (n2 < NTOT) {
            float a = bt;
            a = DOT2(U2H(S[oo].clsP[0]), U2H(w0.x), a);
            a = DOT2(U2H(S[oo].clsP[1]), U2H(w0.y), a);
            a = DOT2(U2H(S[oo].clsP[2]), U2H(w0.z), a);
            a = DOT2(U2H(S[oo].clsP[3]), U2H(w0.w), a);
            a = DOT2(U2H(S[oo].clsP[4]), U2H(w1.x), a);
            a = DOT2(U2H(S[oo].clsP[5]), U2H(w1.y), a);
            a = DOT2(U2H(S[oo].clsP[6]), U2H(w1.z), a);
            a = DOT2(U2H(S[oo].clsP[7]), U2H(w1.w), a);
            out[((long)(n2 >> 9) * 256 + ut) * 512 + (n2 & 511)] = a;
        }
    }
}

extern "C" void kernel_launch(void* const* d_in, const int* in_sizes, int n_in,
                              void* d_out, int out_size, void* d_ws, size_t ws_size,
                              hipStream_t stream) {
    const float* cf       = (const float*)d_in[0];
    const float* fe       = (const float*)d_in[1];
    const float* fb       = (const float*)d_in[2];
    const float* cls_tok  = (const float*)d_in[3];
    const float* te       = (const float*)d_in[4];
    const int*   role_ids = (const int*)  d_in[5];
    const float* ln1_s    = (const float*)d_in[6];
    const float* ln1_b    = (const float*)d_in[7];
    const float* qkv_w    = (const float*)d_in[8];
    const float* qkv_b    = (const float*)d_in[9];
    const float* out_w    = (const float*)d_in[10];
    const float* out_b    = (const float*)d_in[11];
    const float* ln2_s    = (const float*)d_in[12];
    const float* ln2_b    = (const float*)d_in[13];
    const float* ff1_w    = (const float*)d_in[14];
    const float* ff1_b    = (const float*)d_in[15];
    const float* ff2_w    = (const float*)d_in[16];
    const float* ff2_b    = (const float*)d_in[17];
    const float* c2h_w    = (const float*)d_in[18];
    const float* c2h_b    = (const float*)d_in[19];
    float* out = (float*)d_out;
    unsigned* ws = (unsigned*)d_ws;

    pack_kernel<<<1, 256, 0, stream>>>(qkv_w, qkv_b, out_w, out_b, ff1_w, ff1_b,
                                       ff2_w, ff2_b, c2h_w, c2h_b, fb, te,
                                       role_ids, ws);
    const int nblocks = (NTOT + NS - 1) / NS;   // 6554
    enc_kernel<<<nblocks, 256, 0, stream>>>(cf, fe, cls_tok, ln1_s, ln1_b,
                                            ln2_s, ln2_b, ws, out);
}